// Round 13
// baseline (495.282 us; speedup 1.0000x reference)
//
#include <hip/hip_runtime.h>
#include <hip/hip_bf16.h>

// Model: one_hot -> 3x Conv2D(5,(4,4),(1,2),SAME) -> [B,S=1024,D=20]
//        -> 3x causal self-attention -> flatten -> 3x Dense(10)
// B=64, L=8192, S=1024, D=20.
// R23 (198.5): attn 512-thr (q-subtile,t-half), V^T staged once, K direct.
// R31 (195.9, best): dense head composed (affine): out = X@(W1@W2@W3)+Bc;
//      attn3 atomicAdds partials into bias-initialized out. 5 launches.
// R32: conv12 + conv3_proj FUSED (4 launches). Dependency is block-local:
//      256 conv3 outputs need exactly 514 c2 columns. R29's failure was the
//      256-thread staging loop (2 trips -> compiler software-pipelined two
//      full conv12 bodies -> VGPR 256 + spills). Fix: 512 threads, ONE
//      column per thread (#pragma unroll 1 for the 2-extra trip), phase 2 on
//      threads 0-255 verbatim. c2 (47MB round trip) never touches HBM.
//      Attn/dense = R31 byte-for-byte. Bit-identical output.

#define B_ 64
#define L_ 8192
#define S_ 1024
#define D_ 20

typedef unsigned short ushort_t;
typedef __attribute__((ext_vector_type(8))) short short8_t;  // 8 bf16 (4 VGPRs)
typedef __attribute__((ext_vector_type(4))) short short4_t;  // 4 bf16 (2 VGPRs)
typedef __attribute__((ext_vector_type(4))) float f32x4_t;   // MFMA C/D

__device__ __forceinline__ ushort_t f2bf(float f) {          // RNE fp32->bf16
  unsigned u = __float_as_uint(f);
  return (ushort_t)((u + 0x7fffu + ((u >> 16) & 1u)) >> 16);
}
__device__ __forceinline__ float bf2f(ushort_t h) {
  return __uint_as_float(((unsigned)h) << 16);
}

// ---- fused conv1+conv2+conv3+proj (+ composed-W1T tail + out bias) ------
// Block = 256 conv3 outputs (b = blk>>2, wo in [wo0, wo0+256)). 512 threads.
// Phase 1: thread stages ONE c2 column (sidx=tid; tid<2 take 512+tid) with
// the exact conv12 FMA order -> bit-identical. Out-of-range columns = 0
// (conv3 SAME padding). Phase 2: threads 0-255 run conv3+proj from LDS.
__global__ __launch_bounds__(512) void conv_fused_kernel(
    const int* __restrict__ inp,
    const float* __restrict__ W1c, const float* __restrict__ B1c,
    const float* __restrict__ W2c, const float* __restrict__ B2c,
    const float* __restrict__ W3c, const float* __restrict__ B3c,
    const float* __restrict__ Kw,  const float* __restrict__ Qw,
    const float* __restrict__ Vw,
    ushort_t* __restrict__ Qb, ushort_t* __restrict__ Kb,
    ushort_t* __restrict__ Vt,                    // V^T [b][32][1024]
    const float* __restrict__ W1d,                // dense W1 [20480,10]
    float* __restrict__ W1T,                      // [10,20480] COMPOSED
    const float* __restrict__ B1d, const float* __restrict__ W2d,
    const float* __restrict__ B2d, const float* __restrict__ W3d,
    const float* __restrict__ B3d,
    float* __restrict__ outp) {                   // [64,10] bias-initialized
  __shared__ float w1s[80], b1s[5], w2s[400], b2s[5];
  __shared__ float ws3[400], bs3[5];
  __shared__ float kws[400], qws[400], vws[400];
  __shared__ float c2s[514 * 21];                 // staged c2 cols (pad 21)
  const int tid = threadIdx.x;
  const int blk = blockIdx.x;                     // 256 blocks
  for (int i = tid; i < 400; i += 512) {
    w2s[i] = W2c[i]; ws3[i] = W3c[i];
    kws[i] = Kw[i];  qws[i] = Qw[i];  vws[i] = Vw[i];
  }
  if (tid < 80)       w1s[tid]      = W1c[tid];
  else if (tid < 85)  b1s[tid - 80] = B1c[tid - 80];
  else if (tid < 90)  b2s[tid - 85] = B2c[tid - 85];
  else if (tid < 95)  bs3[tid - 90] = B3c[tid - 90];
  __syncthreads();
  const int b   = blk >> 2;
  const int wo0 = (blk & 3) << 8;
  const int* ib = inp + (size_t)b * L_;
  // ---- phase 1: one column per thread (exact conv12 body) ----
#pragma unroll 1
  for (int sidx = tid; sidx < 514; sidx += 512) { // tid<2 run 2 trips
    const int wi = 2 * wo0 - 1 + sidx;
    float acc[4][5];
    if (wi >= 0 && wi < 2048) {
      int iv[10];
#pragma unroll
      for (int t = 0; t < 10; ++t) {
        int g = 4 * wi - 3 + t;
        iv[t] = (g >= 0 && g < L_) ? ib[g] : -100;  // sentinel
      }
      float val[4][4][5];                           // [hi][pos][ci]
#pragma unroll
      for (int pos = 0; pos < 4; ++pos) {
        const int w1 = 2 * wi - 1 + pos;
        const bool okp = (w1 >= 0 && w1 < 4096);    // conv2 SAME pad -> 0
#pragma unroll
        for (int hi = 0; hi < 4; ++hi)
#pragma unroll
          for (int ci = 0; ci < 5; ++ci) val[hi][pos][ci] = okp ? b1s[ci] : 0.f;
        if (okp) {
#pragma unroll
          for (int kw = 0; kw < 4; ++kw) {
            const int gw = 2 * w1 - 1 + kw;
            if (gw >= 0 && gw < L_) {
              const int v = iv[2 * pos + kw];
#pragma unroll
              for (int hi = 0; hi < 4; ++hi) {
                const int kh = v - hi + 1;
                if (kh >= 0 && kh < 4) {
#pragma unroll
                  for (int ci = 0; ci < 5; ++ci)
                    val[hi][pos][ci] += w1s[(kh * 4 + kw) * 5 + ci];
                }
              }
            }
          }
        }
      }
#pragma unroll
      for (int h = 0; h < 4; ++h)
#pragma unroll
        for (int c = 0; c < 5; ++c) acc[h][c] = b2s[c];
#pragma unroll
      for (int kh = 0; kh < 4; ++kh)
#pragma unroll
        for (int kw = 0; kw < 4; ++kw)
#pragma unroll
          for (int ci = 0; ci < 5; ++ci) {
            const float* wp = w2s + ((kh * 4 + kw) * 5 + ci) * 5;
            float w0 = wp[0], w1v = wp[1], w2v = wp[2], w3v = wp[3], w4v = wp[4];
#pragma unroll
            for (int h = 0; h < 4; ++h) {
              int hi = h - 1 + kh;
              if (hi >= 0 && hi < 4) {
                float x = val[hi][kw][ci];
                acc[h][0] += w0 * x;  acc[h][1] += w1v * x; acc[h][2] += w2v * x;
                acc[h][3] += w3v * x; acc[h][4] += w4v * x;
              }
            }
          }
    } else {
#pragma unroll
      for (int h = 0; h < 4; ++h)
#pragma unroll
        for (int c = 0; c < 5; ++c) acc[h][c] = 0.f;  // conv3 SAME padding
    }
#pragma unroll
    for (int h = 0; h < 4; ++h)
#pragma unroll
      for (int c = 0; c < 5; ++c) c2s[sidx * 21 + h * 5 + c] = acc[h][c];
  }
  __syncthreads();
  // ---- phase 2: conv3 + proj (threads 0..255; exact conv3_proj body) ----
  if (tid < 256) {
    const int wo = wo0 + tid;
    const int r  = (b << 10) + wo;
    float val[4][4][5];
#pragma unroll
    for (int kwp = 0; kwp < 4; ++kwp) {
      const int lidx = 2 * tid + kwp;             // = wi - (2*wo0 - 1)
#pragma unroll
      for (int hi = 0; hi < 4; ++hi)
#pragma unroll
        for (int ci = 0; ci < 5; ++ci)
          val[hi][kwp][ci] = c2s[lidx * 21 + hi * 5 + ci];
    }
    float acc[4][5];
#pragma unroll
    for (int h = 0; h < 4; ++h)
#pragma unroll
      for (int c = 0; c < 5; ++c) acc[h][c] = bs3[c];
#pragma unroll
    for (int kh = 0; kh < 4; ++kh)
#pragma unroll
      for (int kwp = 0; kwp < 4; ++kwp)
#pragma unroll
        for (int ci = 0; ci < 5; ++ci) {
          const float* wp = ws3 + ((kh * 4 + kwp) * 5 + ci) * 5;
          float w0 = wp[0], w1 = wp[1], w2 = wp[2], w3 = wp[3], w4 = wp[4];
#pragma unroll
          for (int h = 0; h < 4; ++h) {
            int hi = h - 1 + kh;
            if (hi >= 0 && hi < 4) {
              float x = val[hi][kwp][ci];
              acc[h][0] += w0 * x; acc[h][1] += w1 * x; acc[h][2] += w2 * x;
              acc[h][3] += w3 * x; acc[h][4] += w4 * x;
            }
          }
        }
    float x[D_];
#pragma unroll
    for (int h = 0; h < 4; ++h)
#pragma unroll
      for (int c = 0; c < 5; ++c) x[h * 5 + c] = acc[h][c];
    float q[D_], k[D_], v[D_];
#pragma unroll
    for (int j = 0; j < D_; ++j) { q[j] = 0.f; k[j] = 0.f; v[j] = 0.f; }
#pragma unroll
    for (int i = 0; i < D_; ++i) {
#pragma unroll
      for (int j = 0; j < D_; ++j) {
        q[j] += x[i] * qws[i * D_ + j];
        k[j] += x[i] * kws[i * D_ + j];
        v[j] += x[i] * vws[i * D_ + j];
      }
    }
    const float sc = 0.22360679774997896f;  // 1/sqrt(20)
    ushort_t qt[32], kt[32];
#pragma unroll
    for (int j = 0; j < D_; ++j) { qt[j] = f2bf(q[j] * sc); kt[j] = f2bf(k[j]); }
#pragma unroll
    for (int j = D_; j < 32; ++j) { qt[j] = 0; kt[j] = 0; }
    int4* qd = (int4*)(Qb + (size_t)r * 32);
    int4* kd = (int4*)(Kb + (size_t)r * 32);
#pragma unroll
    for (int j = 0; j < 4; ++j) {
      qd[j] = *(const int4*)(qt + 8 * j);
      kd[j] = *(const int4*)(kt + 8 * j);
    }
    ushort_t* vbase = Vt + ((size_t)b * 32) * 1024 + wo;
#pragma unroll
    for (int d = 0; d < D_; ++d) vbase[d * 1024] = f2bf(v[d]);
  }
  // ---- tail: COMPOSED W1T_c + out bias init (all 512 threads) ----
  const int gidx = blk * 512 + tid;               // 131072 total
  for (int j = gidx; j < 204800; j += 131072) {
    const int col = j / 20480, i2 = j - col * 20480;
    float w23[10];
#pragma unroll
    for (int k2 = 0; k2 < 10; ++k2) {
      float s = 0.f;
#pragma unroll
      for (int m = 0; m < 10; ++m) s += W2d[k2 * 10 + m] * W3d[m * 10 + col];
      w23[k2] = s;
    }
    float s = 0.f;
#pragma unroll
    for (int k2 = 0; k2 < 10; ++k2) s += W1d[i2 * 10 + k2] * w23[k2];
    W1T[j] = s;
  }
  if (gidx < 640) {
    const int col = gidx - (gidx / 10) * 10;
    float bc = B3d[col];
#pragma unroll
    for (int m = 0; m < 10; ++m) bc += B2d[m] * W3d[m * 10 + col];
#pragma unroll
    for (int k2 = 0; k2 < 10; ++k2) {
      float w23 = 0.f;
#pragma unroll
      for (int m = 0; m < 10; ++m) w23 += W2d[k2 * 10 + m] * W3d[m * 10 + col];
      bc += B1d[k2] * w23;
    }
    outp[gidx] = bc;
  }
}

// ---------------- causal attention: 8 waves = (q-subtile, t-half) ---------
// S^T = mfma_16x16x32(Kfrag, Qfrag): lane (quad,n): S^T[t=quad*4+r][q=n].
// P^T register layout IS the B-operand of mfma_16x16x16; PV from registers.
// V^T rows 0..19 staged ONCE (stride 1032 us); K direct from global.
// Zero main-loop barriers. (R23/R31 verbatim.)
// FUSE=true : epilogue projects O rows -> next layer's Qb2/Kb2/Vt2.
// FUSE=false: epilogue atomicAdds composed-dense partials into outp[b][10].
template <bool FUSE>
__global__ __launch_bounds__(512, 6) void attn_kernel(
    const ushort_t* __restrict__ Qb, const ushort_t* __restrict__ Kb,
    const ushort_t* __restrict__ Vt,
    const float* __restrict__ Kw2, const float* __restrict__ Qw2,
    const float* __restrict__ Vw2,
    ushort_t* __restrict__ Qb2, ushort_t* __restrict__ Kb2,
    ushort_t* __restrict__ Vt2,
    const float* __restrict__ W1T,   // !FUSE: composed [10,20480]
    float* __restrict__ outp) {      // !FUSE: [64,10] (bias-initialized)
  constexpr int VST = 1032;                   // ushort stride (pad 8)
  __shared__ ushort_t vts[20 * VST];          // 41,280 B
  __shared__ float extraf[FUSE ? 2480 : 1280]; // FUSE: pw 1200 + ox 1280
  __shared__ float mrgL[64];                  // half1 l partials [sub][n]
  __shared__ float red2[FUSE ? 4 : 40];       // !FUSE: per-wave dense sums
  const int blk   = blockIdx.x;
  const int b     = blk & 63;                 // blk%8==b%8 -> XCD locality
  const int strip = 15 - (blk >> 6);          // heavy strips dispatch first
  const int q0    = strip * 64;
  const int nt    = q0 + 64;
  const int tid   = threadIdx.x;
  const int w     = tid >> 6;                 // wave 0..7
  const int sub   = w & 3;                    // q-subtile
  const int half  = w >> 2;                   // t-half
  const int lane  = tid & 63;
  const int n     = lane & 15;
  const int quad  = lane >> 4;
  const int qbase = q0 + 16 * sub;
  const int qg    = qbase + n;                // this lane's q column
  // ---- stage V^T rows 0..19, t < nt (once; no other barriers) ----
  const ushort_t* VtB = Vt + (size_t)b * 32 * 1024;
  const int ntc = nt >> 3;                    // 16B chunks per row
  for (int i = tid; i < 20 * ntc; i += 512) {
    int row = i / ntc, cc = i - row * ntc;
    *(int4*)(vts + row * VST + cc * 8) =
        *(const int4*)(VtB + (size_t)row * 1024 + cc * 8);
  }
  if (FUSE) {
    for (int j = tid; j < 1200; j += 512) {
      int m = j / 400, oo = j - m * 400;
      extraf[j] = (m == 0) ? Kw2[oo] : (m == 1) ? Qw2[oo] : Vw2[oo];
    }
  }
  const ushort_t* KbB = Kb + (size_t)b * 1024 * 32;
  short8_t qfrag = *(const short8_t*)(Qb + ((size_t)(b * 1024 + qbase + n)) * 32 + quad * 8);
  f32x4_t oA = {0.f, 0.f, 0.f, 0.f};          // O^T[d=quad*4+r][q=n]
  f32x4_t oB = {0.f, 0.f, 0.f, 0.f};          // O^T[d=16+quad*4+r][q=n] (quad0)
  const f32x4_t zero = {0.f, 0.f, 0.f, 0.f};
  float lsum = 0.f;
  const int nt2 = nt >> 1;
  const int tlo = half ? nt2 : 0;
  int thi = half ? nt : nt2;
  if (thi > qbase + 16) thi = qbase + 16;     // wave-uniform: skip all-masked
  __syncthreads();                            // vts (+pw) visible
  for (int t0 = tlo; t0 < thi; t0 += 32) {
    short8_t kf0 = *(const short8_t*)(KbB + (size_t)(t0 + n) * 32 + quad * 8);
    short8_t kf1 = *(const short8_t*)(KbB + (size_t)(t0 + 16 + n) * 32 + quad * 8);
#pragma unroll
    for (int c = 0; c < 2; ++c) {
      const int tg = t0 + c * 16 + quad * 4;  // global t of r=0
      f32x4_t s = __builtin_amdgcn_mfma_f32_16x16x32_bf16(c ? kf1 : kf0, qfrag,
                                                          zero, 0, 0, 0);
      ushort_t pk4[4];
#pragma unroll
      for (int r = 0; r < 4; ++r) {
        float p = (tg + r <= qg) ? __expf(s[r]) : 0.f;
        ushort_t h = f2bf(p);
        lsum += bf2f(h);                      // consistent with bf16 P in PV
        pk4[r] = h;
      }
      short4_t pfrag = *(const short4_t*)pk4; // B16-frag: k=quad*4+j, n=q
      short4_t vlo = *(const short4_t*)(vts + n * VST + t0 + c * 16 + quad * 4);
      short4_t vhi = *(const short4_t*)(vts + (16 + (n & 3)) * VST + t0 + c * 16 + quad * 4);
      oA = __builtin_amdgcn_mfma_f32_16x16x16bf16_1k(vlo, pfrag, oA, 0, 0, 0);
      oB = __builtin_amdgcn_mfma_f32_16x16x16bf16_1k(vhi, pfrag, oB, 0, 0, 0);
    }
  }
  // l[q=n]: reduce partial sums across the 4 quads
  float l = lsum;
  l += __shfl_xor(l, 16, 64);
  l += __shfl_xor(l, 32, 64);
  // ---- merge halves: half1 writes partials (ox layout), half0 adds ----
  float* ox  = FUSE ? (extraf + 1200) : extraf;   // [1280] = 4 x 320
  float* oxw = ox + sub * 320;
  if (half) {
#pragma unroll
    for (int r = 0; r < 4; ++r) oxw[n * 20 + quad * 4 + r] = oA[r];
    if (quad == 0) {
#pragma unroll
      for (int r = 0; r < 4; ++r) oxw[n * 20 + 16 + r] = oB[r];
      mrgL[sub * 16 + n] = l;
    }
  }
  __syncthreads();
  if (!half) {
#pragma unroll
    for (int r = 0; r < 4; ++r) oA[r] += oxw[n * 20 + quad * 4 + r];
    if (quad == 0) {
#pragma unroll
      for (int r = 0; r < 4; ++r) oB[r] += oxw[n * 20 + 16 + r];
    }
    l += mrgL[sub * 16 + n];                  // broadcast read per n
    const float inv = 1.f / l;
    // overwrite own region with normalized O (same addrs each lane read)
#pragma unroll
    for (int r = 0; r < 4; ++r) oxw[n * 20 + quad * 4 + r] = oA[r] * inv;
    if (quad == 0) {
#pragma unroll
      for (int r = 0; r < 4; ++r) oxw[n * 20 + 16 + r] = oB[r] * inv;
    }
  }
  if (FUSE) {
    if (!half) {
      float* pw = extraf;
      __asm__ volatile("s_waitcnt lgkmcnt(0)" ::: "memory");  // wave LDS RAW
      const int row  = lane >> 2;     // 0..15
      const int part = lane & 3;      // cols 5*part .. 5*part+4
      float x[D_];
#pragma unroll
      for (int i = 0; i < D_; ++i) x[i] = oxw[row * 20 + i];
      float qv[5], kv[5], vv[5];
#pragma unroll
      for (int jj = 0; jj < 5; ++jj) { qv[jj] = 0.f; kv[jj] = 0.f; vv[jj] = 0.f; }
#pragma unroll
      for (int i = 0; i < D_; ++i) {
        const float xi = x[i];
#pragma unroll
        for (int jj = 0; jj < 5; ++jj) {
          const int j = 5 * part + jj;
          kv[jj] += xi * pw[i * 20 + j];          // K block
          qv[jj] += xi * pw[400 + i * 20 + j];    // Q block
          vv[jj] += xi * pw[800 + i * 20 + j];    // V block
        }
      }
      const float sc = 0.22360679774997896f;
      const int rg = b * 1024 + qbase + row;
      const int s  = rg & 1023;
#pragma unroll
      for (int jj = 0; jj < 5; ++jj) {
        const int j = 5 * part + jj;
        Kb2[(size_t)rg * 32 + j] = f2bf(kv[jj]);
        Qb2[(size_t)rg * 32 + j] = f2bf(qv[jj] * sc);
        Vt2[(size_t)b * 32768 + (size_t)j * 1024 + s] = f2bf(vv[jj]);
      }
      if (part == 0) {
#pragma unroll
        for (int u = 0; u < 6; ++u)
          *(unsigned*)(Kb2 + (size_t)rg * 32 + 20 + 2 * u) = 0u;
      } else if (part == 1) {
#pragma unroll
        for (int u = 0; u < 6; ++u)
          *(unsigned*)(Qb2 + (size_t)rg * 32 + 20 + 2 * u) = 0u;
      }
    }
  } else {
    // ---- fused composed-dense partial over this block's 64 rows ----
    __syncthreads();                     // normalized ox visible to all
    float acc[10];
#pragma unroll
    for (int j = 0; j < 10; ++j) acc[j] = 0.f;
    const int base = q0 * 20;
    if (tid < 256) {
#pragma unroll
      for (int k = 0; k < 5; ++k) {
        const int il = tid + 256 * k;
        const float xv = ox[il];
#pragma unroll
        for (int j = 0; j < 10; ++j)
          acc[j] += xv * W1T[(size_t)j * 20480 + base + il];  // lane-coalesced
      }
    }
    // wave butterfly reduce (tid>=256 contribute zeros)
#pragma unroll
    for (int off = 1; off < 64; off <<= 1) {
#pragma unroll
      for (int j = 0; j < 10; ++j) acc[j] += __shfl_xor(acc[j], off, 64);
    }
    if (tid < 256 && lane == 0) {
#pragma unroll
      for (int j = 0; j < 10; ++j) red2[w * 10 + j] = acc[j];
    }
    __syncthreads();
    if (tid < 10) {
      float s2 = red2[tid] + red2[10 + tid] + red2[20 + tid] + red2[30 + tid];
      atomicAdd(&outp[b * 10 + tid], s2);   // out pre-initialized with bias
    }
  }
}

extern "C" void kernel_launch(void* const* d_in, const int* in_sizes, int n_in,
                              void* d_out, int out_size, void* d_ws, size_t ws_size,
                              hipStream_t stream) {
  const int*   inp = (const int*)d_in[0];
  const float* cw1 = (const float*)d_in[1];
  const float* cb1 = (const float*)d_in[2];
  const float* cw2 = (const float*)d_in[3];
  const float* cb2 = (const float*)d_in[4];
  const float* cw3 = (const float*)d_in[5];
  const float* cb3 = (const float*)d_in[6];
  const float* a1K = (const float*)d_in[7];
  const float* a1Q = (const float*)d_in[8];
  const float* a1V = (const float*)d_in[9];
  const float* a2K = (const float*)d_in[10];
  const float* a2Q = (const float*)d_in[11];
  const float* a2V = (const float*)d_in[12];
  const float* a3K = (const float*)d_in[13];
  const float* a3Q = (const float*)d_in[14];
  const float* a3V = (const float*)d_in[15];
  const float* dw1 = (const float*)d_in[16];
  const float* db1 = (const float*)d_in[17];
  const float* dw2 = (const float*)d_in[18];
  const float* db2 = (const float*)d_in[19];
  const float* dw3 = (const float*)d_in[20];
  const float* db3 = (const float*)d_in[21];
  float* outp = (float*)d_out;

  // workspace layout (float units) — R31 offsets (c2 region now unused)
  float* wsf = (float*)d_ws;
  ushort_t* qbA  = (ushort_t*)(wsf);            // [65536][32] bf16  [0 .. 1,048,576)
  ushort_t* kbA  = (ushort_t*)(wsf + 1048576);  //                   [1,048,576 .. 2,097,152)
  ushort_t* vtA  = (ushort_t*)(wsf + 2097152);  // [B,32,S]          [2,097,152 .. 3,145,728)
  float*    w1t  = wsf + 4466688;               // [10,20480] COMPOSED, ends 4,671,488
  ushort_t* qbB  = (ushort_t*)(wsf + 4671488);  // ends 5,195,776
  ushort_t* kbB  = (ushort_t*)(wsf + 5712384);
  ushort_t* vtB  = (ushort_t*)(wsf + 6760960);

  conv_fused_kernel<<<256, 512, 0, stream>>>(
      inp, cw1, cb1, cw2, cb2, cw3, cb3, a1K, a1Q, a1V, qbA, kbA, vtA,
      dw1, w1t, db1, dw2, db2, dw3, db3, outp);
  // attn1: reads A, fused proj(layer2) -> B
  attn_kernel<true><<<1024, 512, 0, stream>>>(
      qbA, kbA, vtA, a2K, a2Q, a2V, qbB, kbB, vtB, nullptr, nullptr);
  // attn2: reads B, fused proj(layer3) -> A
  attn_kernel<true><<<1024, 512, 0, stream>>>(
      qbB, kbB, vtB, a3K, a3Q, a3V, qbA, kbA, vtA, nullptr, nullptr);
  // attn3: reads A, fused composed-dense -> atomicAdd outp
  attn_kernel<false><<<1024, 512, 0, stream>>>(
      qbA, kbA, vtA, nullptr, nullptr, nullptr, nullptr, nullptr, nullptr,
      w1t, outp);
}

// Round 14
// 197.933 us; speedup vs baseline: 2.5023x; 2.5023x over previous
//
#include <hip/hip_runtime.h>
#include <hip/hip_bf16.h>

// Model: one_hot -> 3x Conv2D(5,(4,4),(1,2),SAME) -> [B,S=1024,D=20]
//        -> 3x causal self-attention -> flatten -> 3x Dense(10)
// B=64, L=8192, S=1024, D=20.
// R31 (195.9us, SESSION BEST — this file): R23 attn (512-thr, 8 waves =
//      (q-subtile, t-half), V^T staged once, zero main-loop barriers,
//      K direct-global, masked-group skip) + AFFINE-COMPOSED dense head:
//      out = X@(W1@W2@W3) + (B1@W2@W3 + B2@W3 + B3). conv12's tail emits
//      composed W1T_c and bias-initializes out; attn3 atomicAdds partials.
//      5 launches, no dense_final.
// R32 (495us, REVERTED): conv12+conv3 fusion -> scratch spill pump
//      (WRITE 435MB). Conv fusion is structurally hostile to regalloc
//      (2nd failure after R29); lever closed.
// FLOOR: ~110us harness fill/graph + ~70us latency-dominated kernels +
//      ~15us launch gaps. All intra-kernel levers measured null (±3us).

#define B_ 64
#define L_ 8192
#define S_ 1024
#define D_ 20

typedef unsigned short ushort_t;
typedef __attribute__((ext_vector_type(8))) short short8_t;  // 8 bf16 (4 VGPRs)
typedef __attribute__((ext_vector_type(4))) short short4_t;  // 4 bf16 (2 VGPRs)
typedef __attribute__((ext_vector_type(4))) float f32x4_t;   // MFMA C/D

__device__ __forceinline__ ushort_t f2bf(float f) {          // RNE fp32->bf16
  unsigned u = __float_as_uint(f);
  return (ushort_t)((u + 0x7fffu + ((u >> 16) & 1u)) >> 16);
}
__device__ __forceinline__ float bf2f(ushort_t h) {
  return __uint_as_float(((unsigned)h) << 16);
}

// ------- fused conv1+conv2 (+ composed-W1T tail + out bias init) ---------
__global__ __launch_bounds__(256) void conv12_kernel(
    const int* __restrict__ inp,
    const float* __restrict__ W1c, const float* __restrict__ B1c,
    const float* __restrict__ W2c, const float* __restrict__ B2c,
    float* __restrict__ out,                      // c2 [B,4,2048,5]
    const float* __restrict__ W1d,                // dense W1 [20480,10]
    float* __restrict__ W1T,                      // [10,20480] COMPOSED
    const float* __restrict__ B1d, const float* __restrict__ W2d,
    const float* __restrict__ B2d, const float* __restrict__ W3d,
    const float* __restrict__ B3d,
    float* __restrict__ outp) {                   // [64,10] bias-initialized
  __shared__ float w1s[80], b1s[5], w2s[400], b2s[5];
  for (int j = threadIdx.x; j < 400; j += 256) w2s[j] = W2c[j];
  if (threadIdx.x < 80)      w1s[threadIdx.x]      = W1c[threadIdx.x];
  else if (threadIdx.x < 85) b1s[threadIdx.x - 80] = B1c[threadIdx.x - 80];
  else if (threadIdx.x < 90) b2s[threadIdx.x - 85] = B2c[threadIdx.x - 85];
  __syncthreads();
  const int idx = blockIdx.x * 256 + threadIdx.x;  // 131072 total
  const int b  = idx >> 11;
  const int wo = idx & 2047;
  const int* ib = inp + (size_t)b * L_;
  int iv[10];
#pragma unroll
  for (int t = 0; t < 10; ++t) {
    int g = 4 * wo - 3 + t;
    iv[t] = (g >= 0 && g < L_) ? ib[g] : -100;   // sentinel: no kh matches
  }
  float val[4][4][5];                            // [hi][pos][ci]
#pragma unroll
  for (int pos = 0; pos < 4; ++pos) {
    const int w1 = 2 * wo - 1 + pos;
    const bool okp = (w1 >= 0 && w1 < 4096);     // conv2 SAME padding -> 0
#pragma unroll
    for (int hi = 0; hi < 4; ++hi)
#pragma unroll
      for (int ci = 0; ci < 5; ++ci) val[hi][pos][ci] = okp ? b1s[ci] : 0.f;
    if (okp) {
#pragma unroll
      for (int kw = 0; kw < 4; ++kw) {
        const int gw = 2 * w1 - 1 + kw;
        if (gw >= 0 && gw < L_) {
          const int v = iv[2 * pos + kw];
#pragma unroll
          for (int hi = 0; hi < 4; ++hi) {
            const int kh = v - hi + 1;
            if (kh >= 0 && kh < 4) {
#pragma unroll
              for (int ci = 0; ci < 5; ++ci)
                val[hi][pos][ci] += w1s[(kh * 4 + kw) * 5 + ci];
            }
          }
        }
      }
    }
  }
  float acc[4][5];
#pragma unroll
  for (int h = 0; h < 4; ++h)
#pragma unroll
    for (int c = 0; c < 5; ++c) acc[h][c] = b2s[c];
#pragma unroll
  for (int kh = 0; kh < 4; ++kh)
#pragma unroll
    for (int kw = 0; kw < 4; ++kw)
#pragma unroll
      for (int ci = 0; ci < 5; ++ci) {
        const float* wp = w2s + ((kh * 4 + kw) * 5 + ci) * 5;
        float w0 = wp[0], w1v = wp[1], w2v = wp[2], w3 = wp[3], w4 = wp[4];
#pragma unroll
        for (int h = 0; h < 4; ++h) {
          int hi = h - 1 + kh;
          if (hi >= 0 && hi < 4) {
            float x = val[hi][kw][ci];
            acc[h][0] += w0 * x;  acc[h][1] += w1v * x; acc[h][2] += w2v * x;
            acc[h][3] += w3 * x;  acc[h][4] += w4 * x;
          }
        }
      }
  float* ob = out + (size_t)b * 4 * 2048 * 5;
#pragma unroll
  for (int h = 0; h < 4; ++h)
#pragma unroll
    for (int c = 0; c < 5; ++c) ob[(h * 2048 + wo) * 5 + c] = acc[h][c];
  // ---- tail: COMPOSED W1T_c[col][i2] = sum_k W1[i2,k] * (W2@W3)[k,col] ----
  for (int j = idx; j < 204800; j += 131072) {
    const int col = j / 20480, i2 = j - col * 20480;
    float w23[10];
#pragma unroll
    for (int k2 = 0; k2 < 10; ++k2) {
      float s = 0.f;
#pragma unroll
      for (int m = 0; m < 10; ++m) s += W2d[k2 * 10 + m] * W3d[m * 10 + col];
      w23[k2] = s;
    }
    float s = 0.f;
#pragma unroll
    for (int k2 = 0; k2 < 10; ++k2) s += W1d[i2 * 10 + k2] * w23[k2];
    W1T[j] = s;
  }
  // ---- out init: composed bias Bc = B1@(W2@W3) + B2@W3 + B3 ----
  if (idx < 640) {
    const int col = idx - (idx / 10) * 10;
    float bc = B3d[col];
#pragma unroll
    for (int m = 0; m < 10; ++m) bc += B2d[m] * W3d[m * 10 + col];
#pragma unroll
    for (int k2 = 0; k2 < 10; ++k2) {
      float w23 = 0.f;
#pragma unroll
      for (int m = 0; m < 10; ++m) w23 += W2d[k2 * 10 + m] * W3d[m * 10 + col];
      bc += B1d[k2] * w23;
    }
    outp[idx] = bc;
  }
}

// ---------------- fused conv3 + proj (layer 1) ----------------
__global__ __launch_bounds__(256) void conv3_proj_kernel(
    const float* __restrict__ in,                 // c2 [B,4,2048,5]
    const float* __restrict__ W,  const float* __restrict__ Bi,
    const float* __restrict__ Kw, const float* __restrict__ Qw,
    const float* __restrict__ Vw,
    ushort_t* __restrict__ Qb, ushort_t* __restrict__ Kb,
    ushort_t* __restrict__ Vt) {
  constexpr int WIN = 2048;
  __shared__ float ws[400], bs[5];
  __shared__ float kw[400], qw[400], vw[400];
  for (int j = threadIdx.x; j < 400; j += 256) {
    ws[j] = W[j]; kw[j] = Kw[j]; qw[j] = Qw[j]; vw[j] = Vw[j];
  }
  if (threadIdx.x < 5) bs[threadIdx.x] = Bi[threadIdx.x];
  __syncthreads();
  const int r  = blockIdx.x * 256 + threadIdx.x;  // row in [0, 65536)
  const int b  = r >> 10;
  const int wo = r & 1023;
  float val[4][4][5];
#pragma unroll
  for (int hi = 0; hi < 4; ++hi) {
    const float* ir = in + ((size_t)b * 4 + hi) * WIN * 5;
#pragma unroll
    for (int kwp = 0; kwp < 4; ++kwp) {
      int wi = 2 * wo - 1 + kwp;
      bool ok = (wi >= 0 && wi < WIN);
#pragma unroll
      for (int ci = 0; ci < 5; ++ci) val[hi][kwp][ci] = ok ? ir[wi * 5 + ci] : 0.f;
    }
  }
  float acc[4][5];
#pragma unroll
  for (int h = 0; h < 4; ++h)
#pragma unroll
    for (int c = 0; c < 5; ++c) acc[h][c] = bs[c];
#pragma unroll
  for (int kh = 0; kh < 4; ++kh)
#pragma unroll
    for (int kwp = 0; kwp < 4; ++kwp)
#pragma unroll
      for (int ci = 0; ci < 5; ++ci) {
        const float* wp = ws + ((kh * 4 + kwp) * 5 + ci) * 5;
        float w0 = wp[0], w1 = wp[1], w2 = wp[2], w3 = wp[3], w4 = wp[4];
#pragma unroll
        for (int h = 0; h < 4; ++h) {
          int hi = h - 1 + kh;
          if (hi >= 0 && hi < 4) {
            float x = val[hi][kwp][ci];
            acc[h][0] += w0 * x; acc[h][1] += w1 * x; acc[h][2] += w2 * x;
            acc[h][3] += w3 * x; acc[h][4] += w4 * x;
          }
        }
      }
  float x[D_];
#pragma unroll
  for (int h = 0; h < 4; ++h)
#pragma unroll
    for (int c = 0; c < 5; ++c) x[h * 5 + c] = acc[h][c];
  float q[D_], k[D_], v[D_];
#pragma unroll
  for (int j = 0; j < D_; ++j) { q[j] = 0.f; k[j] = 0.f; v[j] = 0.f; }
#pragma unroll
  for (int i = 0; i < D_; ++i) {
#pragma unroll
    for (int j = 0; j < D_; ++j) {
      q[j] += x[i] * qw[i * D_ + j];
      k[j] += x[i] * kw[i * D_ + j];
      v[j] += x[i] * vw[i * D_ + j];
    }
  }
  const float sc = 0.22360679774997896f;  // 1/sqrt(20)
  ushort_t qt[32], kt[32];
#pragma unroll
  for (int j = 0; j < D_; ++j) { qt[j] = f2bf(q[j] * sc); kt[j] = f2bf(k[j]); }
#pragma unroll
  for (int j = D_; j < 32; ++j) { qt[j] = 0; kt[j] = 0; }
  int4* qd = (int4*)(Qb + (size_t)r * 32);
  int4* kd = (int4*)(Kb + (size_t)r * 32);
#pragma unroll
  for (int j = 0; j < 4; ++j) {
    qd[j] = *(const int4*)(qt + 8 * j);
    kd[j] = *(const int4*)(kt + 8 * j);
  }
  ushort_t* vbase = Vt + ((size_t)b * 32) * 1024 + wo;
#pragma unroll
  for (int d = 0; d < D_; ++d) vbase[d * 1024] = f2bf(v[d]);
}

// ---------------- causal attention: 8 waves = (q-subtile, t-half) ---------
// S^T = mfma_16x16x32(Kfrag, Qfrag): lane (quad,n): S^T[t=quad*4+r][q=n].
// P^T register layout IS the B-operand of mfma_16x16x16; PV from registers.
// V^T rows 0..19 staged ONCE (stride 1032 us); K direct from global
// (16 rows x 64B contiguous per wave instr, L1/L2-hit). Zero main-loop
// barriers. (R23 verbatim main loop.)
// FUSE=true : epilogue projects O rows -> next layer's Qb2/Kb2/Vt2.
// FUSE=false: epilogue atomicAdds composed-dense partials into outp[b][10].
template <bool FUSE>
__global__ __launch_bounds__(512, 6) void attn_kernel(
    const ushort_t* __restrict__ Qb, const ushort_t* __restrict__ Kb,
    const ushort_t* __restrict__ Vt,
    const float* __restrict__ Kw2, const float* __restrict__ Qw2,
    const float* __restrict__ Vw2,
    ushort_t* __restrict__ Qb2, ushort_t* __restrict__ Kb2,
    ushort_t* __restrict__ Vt2,
    const float* __restrict__ W1T,   // !FUSE: composed [10,20480]
    float* __restrict__ outp) {      // !FUSE: [64,10] (bias-initialized)
  constexpr int VST = 1032;                   // ushort stride (pad 8)
  __shared__ ushort_t vts[20 * VST];          // 41,280 B
  __shared__ float extraf[FUSE ? 2480 : 1280]; // FUSE: pw 1200 + ox 1280
  __shared__ float mrgL[64];                  // half1 l partials [sub][n]
  __shared__ float red2[FUSE ? 4 : 40];       // !FUSE: per-wave dense sums
  const int blk   = blockIdx.x;
  const int b     = blk & 63;                 // blk%8==b%8 -> XCD locality
  const int strip = 15 - (blk >> 6);          // heavy strips dispatch first
  const int q0    = strip * 64;
  const int nt    = q0 + 64;
  const int tid   = threadIdx.x;
  const int w     = tid >> 6;                 // wave 0..7
  const int sub   = w & 3;                    // q-subtile
  const int half  = w >> 2;                   // t-half
  const int lane  = tid & 63;
  const int n     = lane & 15;
  const int quad  = lane >> 4;
  const int qbase = q0 + 16 * sub;
  const int qg    = qbase + n;                // this lane's q column
  // ---- stage V^T rows 0..19, t < nt (once; no other barriers) ----
  const ushort_t* VtB = Vt + (size_t)b * 32 * 1024;
  const int ntc = nt >> 3;                    // 16B chunks per row
  for (int i = tid; i < 20 * ntc; i += 512) {
    int row = i / ntc, cc = i - row * ntc;
    *(int4*)(vts + row * VST + cc * 8) =
        *(const int4*)(VtB + (size_t)row * 1024 + cc * 8);
  }
  if (FUSE) {
    for (int j = tid; j < 1200; j += 512) {
      int m = j / 400, oo = j - m * 400;
      extraf[j] = (m == 0) ? Kw2[oo] : (m == 1) ? Qw2[oo] : Vw2[oo];
    }
  }
  const ushort_t* KbB = Kb + (size_t)b * 1024 * 32;
  short8_t qfrag = *(const short8_t*)(Qb + ((size_t)(b * 1024 + qbase + n)) * 32 + quad * 8);
  f32x4_t oA = {0.f, 0.f, 0.f, 0.f};          // O^T[d=quad*4+r][q=n]
  f32x4_t oB = {0.f, 0.f, 0.f, 0.f};          // O^T[d=16+quad*4+r][q=n] (quad0)
  const f32x4_t zero = {0.f, 0.f, 0.f, 0.f};
  float lsum = 0.f;
  const int nt2 = nt >> 1;
  const int tlo = half ? nt2 : 0;
  int thi = half ? nt : nt2;
  if (thi > qbase + 16) thi = qbase + 16;     // wave-uniform: skip all-masked
  __syncthreads();                            // vts (+pw) visible
  for (int t0 = tlo; t0 < thi; t0 += 32) {
    short8_t kf0 = *(const short8_t*)(KbB + (size_t)(t0 + n) * 32 + quad * 8);
    short8_t kf1 = *(const short8_t*)(KbB + (size_t)(t0 + 16 + n) * 32 + quad * 8);
#pragma unroll
    for (int c = 0; c < 2; ++c) {
      const int tg = t0 + c * 16 + quad * 4;  // global t of r=0
      f32x4_t s = __builtin_amdgcn_mfma_f32_16x16x32_bf16(c ? kf1 : kf0, qfrag,
                                                          zero, 0, 0, 0);
      ushort_t pk4[4];
#pragma unroll
      for (int r = 0; r < 4; ++r) {
        float p = (tg + r <= qg) ? __expf(s[r]) : 0.f;
        ushort_t h = f2bf(p);
        lsum += bf2f(h);                      // consistent with bf16 P in PV
        pk4[r] = h;
      }
      short4_t pfrag = *(const short4_t*)pk4; // B16-frag: k=quad*4+j, n=q
      short4_t vlo = *(const short4_t*)(vts + n * VST + t0 + c * 16 + quad * 4);
      short4_t vhi = *(const short4_t*)(vts + (16 + (n & 3)) * VST + t0 + c * 16 + quad * 4);
      oA = __builtin_amdgcn_mfma_f32_16x16x16bf16_1k(vlo, pfrag, oA, 0, 0, 0);
      oB = __builtin_amdgcn_mfma_f32_16x16x16bf16_1k(vhi, pfrag, oB, 0, 0, 0);
    }
  }
  // l[q=n]: reduce partial sums across the 4 quads
  float l = lsum;
  l += __shfl_xor(l, 16, 64);
  l += __shfl_xor(l, 32, 64);
  // ---- merge halves: half1 writes partials (ox layout), half0 adds ----
  float* ox  = FUSE ? (extraf + 1200) : extraf;   // [1280] = 4 x 320
  float* oxw = ox + sub * 320;
  if (half) {
#pragma unroll
    for (int r = 0; r < 4; ++r) oxw[n * 20 + quad * 4 + r] = oA[r];
    if (quad == 0) {
#pragma unroll
      for (int r = 0; r < 4; ++r) oxw[n * 20 + 16 + r] = oB[r];
      mrgL[sub * 16 + n] = l;
    }
  }
  __syncthreads();
  if (!half) {
#pragma unroll
    for (int r = 0; r < 4; ++r) oA[r] += oxw[n * 20 + quad * 4 + r];
    if (quad == 0) {
#pragma unroll
      for (int r = 0; r < 4; ++r) oB[r] += oxw[n * 20 + 16 + r];
    }
    l += mrgL[sub * 16 + n];                  // broadcast read per n
    const float inv = 1.f / l;
    // overwrite own region with normalized O (same addrs each lane read)
#pragma unroll
    for (int r = 0; r < 4; ++r) oxw[n * 20 + quad * 4 + r] = oA[r] * inv;
    if (quad == 0) {
#pragma unroll
      for (int r = 0; r < 4; ++r) oxw[n * 20 + 16 + r] = oB[r] * inv;
    }
  }
  if (FUSE) {
    if (!half) {
      float* pw = extraf;
      __asm__ volatile("s_waitcnt lgkmcnt(0)" ::: "memory");  // wave LDS RAW
      const int row  = lane >> 2;     // 0..15
      const int part = lane & 3;      // cols 5*part .. 5*part+4
      float x[D_];
#pragma unroll
      for (int i = 0; i < D_; ++i) x[i] = oxw[row * 20 + i];
      float qv[5], kv[5], vv[5];
#pragma unroll
      for (int jj = 0; jj < 5; ++jj) { qv[jj] = 0.f; kv[jj] = 0.f; vv[jj] = 0.f; }
#pragma unroll
      for (int i = 0; i < D_; ++i) {
        const float xi = x[i];
#pragma unroll
        for (int jj = 0; jj < 5; ++jj) {
          const int j = 5 * part + jj;
          kv[jj] += xi * pw[i * 20 + j];          // K block
          qv[jj] += xi * pw[400 + i * 20 + j];    // Q block
          vv[jj] += xi * pw[800 + i * 20 + j];    // V block
        }
      }
      const float sc = 0.22360679774997896f;
      const int rg = b * 1024 + qbase + row;
      const int s  = rg & 1023;
#pragma unroll
      for (int jj = 0; jj < 5; ++jj) {
        const int j = 5 * part + jj;
        Kb2[(size_t)rg * 32 + j] = f2bf(kv[jj]);
        Qb2[(size_t)rg * 32 + j] = f2bf(qv[jj] * sc);
        Vt2[(size_t)b * 32768 + (size_t)j * 1024 + s] = f2bf(vv[jj]);
      }
      if (part == 0) {
#pragma unroll
        for (int u = 0; u < 6; ++u)
          *(unsigned*)(Kb2 + (size_t)rg * 32 + 20 + 2 * u) = 0u;
      } else if (part == 1) {
#pragma unroll
        for (int u = 0; u < 6; ++u)
          *(unsigned*)(Qb2 + (size_t)rg * 32 + 20 + 2 * u) = 0u;
      }
    }
  } else {
    // ---- fused composed-dense partial over this block's 64 rows ----
    __syncthreads();                     // normalized ox visible to all
    float acc[10];
#pragma unroll
    for (int j = 0; j < 10; ++j) acc[j] = 0.f;
    const int base = q0 * 20;
    if (tid < 256) {
#pragma unroll
      for (int k = 0; k < 5; ++k) {
        const int il = tid + 256 * k;
        const float xv = ox[il];
#pragma unroll
        for (int j = 0; j < 10; ++j)
          acc[j] += xv * W1T[(size_t)j * 20480 + base + il];  // lane-coalesced
      }
    }
    // wave butterfly reduce (tid>=256 contribute zeros)
#pragma unroll
    for (int off = 1; off < 64; off <<= 1) {
#pragma unroll
      for (int j = 0; j < 10; ++j) acc[j] += __shfl_xor(acc[j], off, 64);
    }
    if (tid < 256 && lane == 0) {
#pragma unroll
      for (int j = 0; j < 10; ++j) red2[w * 10 + j] = acc[j];
    }
    __syncthreads();
    if (tid < 10) {
      float s2 = red2[tid] + red2[10 + tid] + red2[20 + tid] + red2[30 + tid];
      atomicAdd(&outp[b * 10 + tid], s2);   // out pre-initialized with bias
    }
  }
}

extern "C" void kernel_launch(void* const* d_in, const int* in_sizes, int n_in,
                              void* d_out, int out_size, void* d_ws, size_t ws_size,
                              hipStream_t stream) {
  const int*   inp = (const int*)d_in[0];
  const float* cw1 = (const float*)d_in[1];
  const float* cb1 = (const float*)d_in[2];
  const float* cw2 = (const float*)d_in[3];
  const float* cb2 = (const float*)d_in[4];
  const float* cw3 = (const float*)d_in[5];
  const float* cb3 = (const float*)d_in[6];
  const float* a1K = (const float*)d_in[7];
  const float* a1Q = (const float*)d_in[8];
  const float* a1V = (const float*)d_in[9];
  const float* a2K = (const float*)d_in[10];
  const float* a2Q = (const float*)d_in[11];
  const float* a2V = (const float*)d_in[12];
  const float* a3K = (const float*)d_in[13];
  const float* a3Q = (const float*)d_in[14];
  const float* a3V = (const float*)d_in[15];
  const float* dw1 = (const float*)d_in[16];
  const float* db1 = (const float*)d_in[17];
  const float* dw2 = (const float*)d_in[18];
  const float* db2 = (const float*)d_in[19];
  const float* dw3 = (const float*)d_in[20];
  const float* db3 = (const float*)d_in[21];
  float* outp = (float*)d_out;

  // workspace layout (float units) — R23/R19 verbatim
  float* wsf = (float*)d_ws;
  ushort_t* qbA  = (ushort_t*)(wsf);            // [65536][32] bf16  [0 .. 1,048,576)
  ushort_t* kbA  = (ushort_t*)(wsf + 1048576);  //                   [1,048,576 .. 2,097,152)
  ushort_t* vtA  = (ushort_t*)(wsf + 2097152);  // [B,32,S]          [2,097,152 .. 3,145,728)
  float*    w1t  = wsf + 4466688;               // [10,20480] COMPOSED, ends 4,671,488
  ushort_t* qbB  = (ushort_t*)(wsf + 4671488);  // ends 5,195,776
  ushort_t* kbB  = (ushort_t*)(wsf + 5712384);  // B-buffers overlap dead c2 region
  ushort_t* vtB  = (ushort_t*)(wsf + 6760960);  //   (c2 consumed before attn1 writes B)
  float*    c2   = wsf + 5242880;               // [B,4,2048,5]      [5,242,880 .. 7,864,320)

  conv12_kernel<<<512, 256, 0, stream>>>(inp, cw1, cb1, cw2, cb2, c2, dw1,
                                         w1t, db1, dw2, db2, dw3, db3, outp);

  conv3_proj_kernel<<<256, 256, 0, stream>>>(c2, cw3, cb3, a1K, a1Q, a1V,
                                             qbA, kbA, vtA);
  // attn1: reads A, fused proj(layer2) -> B
  attn_kernel<true><<<1024, 512, 0, stream>>>(
      qbA, kbA, vtA, a2K, a2Q, a2V, qbB, kbB, vtB, nullptr, nullptr);
  // attn2: reads B, fused proj(layer3) -> A
  attn_kernel<true><<<1024, 512, 0, stream>>>(
      qbB, kbB, vtB, a3K, a3Q, a3V, qbA, kbA, vtA, nullptr, nullptr);
  // attn3: reads A, fused composed-dense -> atomicAdd outp
  attn_kernel<false><<<1024, 512, 0, stream>>>(
      qbA, kbA, vtA, nullptr, nullptr, nullptr, nullptr, nullptr, nullptr,
      w1t, outp);
}